// Round 7
// baseline (148.377 us; speedup 1.0000x reference)
//
#include <hip/hip_runtime.h>

// Problem constants (fixed by setup_inputs)
#define BSZ   4
#define CCH   320
#define HH    96
#define WW    192
#define NHEAD 16
#define NC    20          // channels per group = 320/16
#define DMAX  64
#define HWSZ  (HH * WW)

typedef _Float16 f16x8 __attribute__((ext_vector_type(8)));
typedef float    f32x4 __attribute__((ext_vector_type(4)));

// MFMA formulation: per (b,g,y) row, out[d,x] = scale * G[x, x+64-d] where
// G[x,u'] = sum_ch L[ch,x] * Rp[ch,u']  (Rp = rf row left-padded 64 zeros).
// Per 16-wide x-tile, u' spans [x0+1, x0+79] -> 5 u'-tiles at U = x0+16j:
//   tile j gives d = 64-16j + m - n  (m,n in [0,16)), each (d,m) covered by
//   exactly one (j,n). One mfma_f32_16x16x32_f16 per (x-tile, j): K=32 with
//   ch 20..31 zeroed on the A side (so B-side garbage is annihilated).
// Epilogue: scatter acc -> per-wave LDS buf[64][24] (d-major), then
// conflict-free b128 reads + float4 global stores (full 64B sectors).
__global__ __launch_bounds__(256) void gwc_kernel(const float* __restrict__ lf,
                                                  const float* __restrict__ rf,
                                                  float* __restrict__ out) {
    __shared__ __align__(16) uint4 lfs[3][WW];          //  9216 B: [kgrp][x]    ch 8g..8g+7 f16x8
    __shared__ __align__(16) uint4 rfs[3][WW + DMAX];   // 12288 B: [kgrp][slot] slot = x+64
    __shared__ __align__(16) float buf[4][DMAX][24];    // 24576 B: per-wave transpose buffer

    const int tid  = threadIdx.x;
    const int wv   = tid >> 6;
    const int lane = tid & 63;
    int bid = blockIdx.x;
    const int y = bid % HH;  bid /= HH;
    const int g = bid % NHEAD; bid /= NHEAD;
    const int b = bid;

    const size_t rowbase = ((size_t)(b * CCH + g * NC) * HH + y) * WW;

    // zero rf pad slots (3 kgrps x 64 slots) -> exact 0 for x < d outputs
    if (tid < 3 * DMAX) rfs[tid / DMAX][tid % DMAX] = make_uint4(0u, 0u, 0u, 0u);

    // stage: item = (kgrp, x); 3*192 = 576 items per tensor; 8 ch each, f32->f16
    for (int it = tid; it < 3 * WW; it += 256) {
        const int x  = it % WW;
        const int kg = it / WW;
        union { f16x8 v; uint4 u; } L, R;
#pragma unroll
        for (int e = 0; e < 8; ++e) {
            const int ch = 8 * kg + e;
            float lv = 0.f, rv = 0.f;
            if (ch < NC) {
                lv = lf[rowbase + (size_t)ch * HWSZ + x];
                rv = rf[rowbase + (size_t)ch * HWSZ + x];
            }
            L.v[e] = (_Float16)lv;   // ch >= 20 -> exact f16 zero (A-side kill)
            R.v[e] = (_Float16)rv;
        }
        lfs[kg][x] = L.u;
        rfs[kg][DMAX + x] = R.u;
    }
    __syncthreads();

    const int n   = lane & 15;          // A row m-index source / B col / C col
    const int kg  = lane >> 4;          // k-group (k = 8*kg + e)
    const int kgc = (kg > 2) ? 2 : kg;  // clamped LDS address (kg==3 is zeroed/ignored)
    const bool ktail = (kg == 3);

    const size_t obase = ((size_t)(b * NHEAD + g) * DMAX) * HWSZ + (size_t)y * WW;
    const float scale = 0.22360679774997896f;  // 1/sqrt(20)
    const int dl = lane >> 2, c4 = lane & 3;   // readback: d = 16p+dl, x = x0+4*c4

    for (int xt = 3 * wv; xt < 3 * wv + 3; ++xt) {
        const int x0 = 16 * xt;

        // A fragment: A[m = lane&15][k = 8*kg+e] = L[ch=k][x0+m]; zero k>=24 lanes
        union { f16x8 v; uint4 u; } Af;
        Af.u = lfs[kgc][x0 + n];
        if (ktail) Af.u = make_uint4(0u, 0u, 0u, 0u);

        f32x4 acc[5];
#pragma unroll
        for (int j = 0; j < 5; ++j) {
            // B fragment: B[k = 8*kg+e][n = lane&15] = Rp[ch=k][x0+16j+n]
            union { f16x8 v; uint4 u; } Bf;
            Bf.u = rfs[kgc][x0 + 16 * j + n];
            acc[j] = __builtin_amdgcn_mfma_f32_16x16x32_f16(
                Af.v, Bf.v, (f32x4){0.f, 0.f, 0.f, 0.f}, 0, 0, 0);
        }

        // scatter: C[m][n] with m = 4*kg+q, n = lane&15; d = 64-16j+m-n
#pragma unroll
        for (int j = 0; j < 5; ++j) {
#pragma unroll
            for (int q = 0; q < 4; ++q) {
                const int m = 4 * kg + q;
                const int d = 64 - 16 * j + m - n;
                if (d >= 0 && d < DMAX) buf[wv][d][m] = acc[j][q];
            }
        }

        // readback (conflict-free b128) + coalesced float4 stores
#pragma unroll
        for (int p = 0; p < 4; ++p) {
            const int d = 16 * p + dl;
            float4 v = *(const float4*)&buf[wv][d][4 * c4];
            v.x *= scale; v.y *= scale; v.z *= scale; v.w *= scale;
            *(float4*)&out[obase + (size_t)d * HWSZ + x0 + 4 * c4] = v;
        }
    }
}

extern "C" void kernel_launch(void* const* d_in, const int* in_sizes, int n_in,
                              void* d_out, int out_size, void* d_ws, size_t ws_size,
                              hipStream_t stream) {
    const float* lf = (const float*)d_in[0];
    const float* rf = (const float*)d_in[1];
    float* out = (float*)d_out;

    const int grid = BSZ * NHEAD * HH;   // 6144 blocks, one (b,g,y) row each
    gwc_kernel<<<grid, 256, 0, stream>>>(lf, rf, out);
}

// Round 8
// 106.686 us; speedup vs baseline: 1.3908x; 1.3908x over previous
//
#include <hip/hip_runtime.h>

// Problem constants (fixed by setup_inputs)
#define HH    96
#define WW    192
#define NHEAD 16
#define NC    20          // channels per group = 320/16
#define DMAX  64
#define HWSZ  (HH * WW)
#define NSLOT (WW + DMAX) // 256 slots (64 zero pad + 192 data)
#define SPAD  12          // uints per slot: 10 half2 + 2 pad -> 48 B, 16B-aligned
#define GRID  1536        // 6 blocks/CU * 256 CU
#define RPB   4           // rows per block; GRID*RPB = 6144 = all (b,g,y) rows

typedef _Float16 half2v __attribute__((ext_vector_type(2)));

#define BC(u) __builtin_bit_cast(half2v, u)

// Persistent double-buffered R6: each block processes RPB rows; rf row staged
// f16 in a 2-buffer LDS ring. Next row's rf global loads issue BEFORE the
// current row's 64-step compute (latency hidden under it); cvt + ds_write to
// the idle buffer after compute; one sync per row. Zero pad slots (both
// buffers) zeroed once -> x<d outputs exact 0. Dot via v_dot2_f32_f16.
__global__ __launch_bounds__(192) void gwc_kernel(const float* __restrict__ lf,
                                                  const float* __restrict__ rf,
                                                  float* __restrict__ out) {
    __shared__ __align__(16) unsigned int rfs[2][NSLOT][SPAD];   // 24576 B

    const int x = threadIdx.x;        // 0..191

    // zero the left pads of BOTH buffers (slots 0..63; never rewritten)
    for (int i = x; i < 2 * DMAX * SPAD; i += 192) {
        const int bsel = i / (DMAX * SPAD);
        const int off  = i % (DMAX * SPAD);
        (&rfs[bsel][0][0])[off] = 0u;
    }

    const float scale = 0.22360679774997896f;   // 1/sqrt(20)
    half2v Lc[10];

    // prologue: stage row0 (lf -> Lc regs, rf -> LDS buf0)
    {
        const int R  = blockIdx.x;
        const int bg = R / HH, y = R % HH;
        const float* lp = lf + (size_t)bg * NC * HWSZ + (size_t)y * WW + x;
        const float* rp = rf + (size_t)bg * NC * HWSZ + (size_t)y * WW + x;
        unsigned int w[10];
#pragma unroll
        for (int j = 0; j < 10; ++j) {
            const float l0 = lp[(size_t)(2 * j) * HWSZ], l1 = lp[(size_t)(2 * j + 1) * HWSZ];
            const float r0 = rp[(size_t)(2 * j) * HWSZ], r1 = rp[(size_t)(2 * j + 1) * HWSZ];
            Lc[j] = half2v{(_Float16)l0, (_Float16)l1};
            w[j]  = __builtin_bit_cast(unsigned int, half2v{(_Float16)r0, (_Float16)r1});
        }
        unsigned int* dst = &rfs[0][DMAX + x][0];
        *(uint4*)(dst + 0) = make_uint4(w[0], w[1], w[2], w[3]);
        *(uint4*)(dst + 4) = make_uint4(w[4], w[5], w[6], w[7]);
        *(uint2*)(dst + 8) = make_uint2(w[8], w[9]);
    }
    __syncthreads();

    for (int r = 0; r < RPB; ++r) {
        // issue next row's rf loads NOW (hidden under this row's compute)
        float rn[20];
        if (r < RPB - 1) {
            const int Rn = blockIdx.x + GRID * (r + 1);
            const int bg = Rn / HH, y = Rn % HH;
            const float* rp = rf + (size_t)bg * NC * HWSZ + (size_t)y * WW + x;
#pragma unroll
            for (int c = 0; c < 20; ++c) rn[c] = rp[(size_t)c * HWSZ];
        }

        // compute row r from buf[r&1]  (R6-proven core)
        {
            const int R  = blockIdx.x + GRID * r;
            const int bg = R / HH, y = R % HH;
            float* op = out + (size_t)bg * DMAX * HWSZ + (size_t)y * WW + x;
            const unsigned int (*buf)[SPAD] = rfs[r & 1];
#pragma unroll 4
            for (int d = 0; d < DMAX; ++d) {
                const unsigned int* Wp = buf[x + DMAX - d];
                const uint4 wA = *(const uint4*)(Wp + 0);   // ch 0-7
                const uint4 wB = *(const uint4*)(Wp + 4);   // ch 8-15
                const uint2 wC = *(const uint2*)(Wp + 8);   // ch 16-19
                float sa = 0.f, sb = 0.f;
                sa = __builtin_amdgcn_fdot2(Lc[0], BC(wA.x), sa, false);
                sb = __builtin_amdgcn_fdot2(Lc[1], BC(wA.y), sb, false);
                sa = __builtin_amdgcn_fdot2(Lc[2], BC(wA.z), sa, false);
                sb = __builtin_amdgcn_fdot2(Lc[3], BC(wA.w), sb, false);
                sa = __builtin_amdgcn_fdot2(Lc[4], BC(wB.x), sa, false);
                sb = __builtin_amdgcn_fdot2(Lc[5], BC(wB.y), sb, false);
                sa = __builtin_amdgcn_fdot2(Lc[6], BC(wB.z), sa, false);
                sb = __builtin_amdgcn_fdot2(Lc[7], BC(wB.w), sb, false);
                sa = __builtin_amdgcn_fdot2(Lc[8], BC(wC.x), sa, false);
                sb = __builtin_amdgcn_fdot2(Lc[9], BC(wC.y), sb, false);
                op[0] = (sa + sb) * scale;
                op += HWSZ;
            }
        }

        // stage next row: fresh lf -> Lc, prefetched rn -> f16 -> idle buffer
        if (r < RPB - 1) {
            const int Rn = blockIdx.x + GRID * (r + 1);
            const int bg = Rn / HH, y = Rn % HH;
            const float* lp = lf + (size_t)bg * NC * HWSZ + (size_t)y * WW + x;
            unsigned int w[10];
#pragma unroll
            for (int j = 0; j < 10; ++j) {
                Lc[j] = half2v{(_Float16)lp[(size_t)(2 * j) * HWSZ],
                               (_Float16)lp[(size_t)(2 * j + 1) * HWSZ]};
                w[j]  = __builtin_bit_cast(unsigned int,
                                           half2v{(_Float16)rn[2 * j], (_Float16)rn[2 * j + 1]});
            }
            unsigned int* dst = &rfs[(r + 1) & 1][DMAX + x][0];
            *(uint4*)(dst + 0) = make_uint4(w[0], w[1], w[2], w[3]);
            *(uint4*)(dst + 4) = make_uint4(w[4], w[5], w[6], w[7]);
            *(uint2*)(dst + 8) = make_uint2(w[8], w[9]);
        }
        __syncthreads();
    }
}

extern "C" void kernel_launch(void* const* d_in, const int* in_sizes, int n_in,
                              void* d_out, int out_size, void* d_ws, size_t ws_size,
                              hipStream_t stream) {
    const float* lf = (const float*)d_in[0];
    const float* rf = (const float*)d_in[1];
    float* out = (float*)d_out;

    gwc_kernel<<<GRID, 192, 0, stream>>>(lf, rf, out);
}

// Round 9
// 104.492 us; speedup vs baseline: 1.4200x; 1.0210x over previous
//
#include <hip/hip_runtime.h>

// Problem constants (fixed by setup_inputs)
#define BSZ   4
#define CCH   320
#define HH    96
#define WW    192
#define NHEAD 16
#define NC    20          // channels per group = 320/16
#define DMAX  64
#define HWSZ  (HH * WW)
#define NSLOT (WW + DMAX) // 256 slots (64 zero pad + 192 data)
#define SPAD  12          // uints per slot: 10 half2 + 2 pad -> 48 B, 16B-aligned
#define NROW  2           // rows per block
#define TPR   96          // threads per row; thread covers x = 2i, 2i+1

typedef _Float16 half2v __attribute__((ext_vector_type(2)));
#define BC(u) __builtin_bit_cast(half2v, u)

// R6 core (f16 LDS slots, 3 LDS reads + 10 dot2 per output, zero-padded slots,
// no loop-carried state) with ONE change: each thread produces TWO adjacent-x
// outputs per d-step, stored as a single float2 -> store instructions halved,
// per-block write chunks 768 B -> 1536 B, lf loads become float2. Pure A/B on
// store width / write-stream granularity vs R6.
__global__ __launch_bounds__(192) void gwc_kernel(const float* __restrict__ lf,
                                                  const float* __restrict__ rf,
                                                  float* __restrict__ out) {
    __shared__ __align__(16) unsigned int rfs[NROW][NSLOT][SPAD];   // 24576 B

    const int tid = threadIdx.x;
    const int r   = tid / TPR;        // row within block
    const int i   = tid % TPR;        // x-pair; x = 2i, 2i+1
    int bid = blockIdx.x;
    const int yp = bid % (HH / NROW); bid /= (HH / NROW);
    const int bg = bid;               // combined (b*NHEAD + g)
    const int y0 = yp * NROW;

    // zero the left pads (slots 0..63 of both rows)
    for (int k = tid; k < NROW * DMAX * SPAD; k += 192) {
        const int rr  = k / (DMAX * SPAD);
        const int off = k % (DMAX * SPAD);
        (&rfs[rr][0][0])[off] = 0u;
    }

    const size_t gbase = (size_t)bg * NC * HWSZ;

    // stage rf: item = (row, x); 2*192 items, 20 scalar f32 -> 10 half2 -> 48 B
    for (int it = tid; it < NROW * WW; it += 192) {
        const int rr = it / WW, x = it % WW;
        const float* rp = rf + gbase + (size_t)(y0 + rr) * WW + x;
        unsigned int w[10];
#pragma unroll
        for (int j = 0; j < 10; ++j) {
            const float v0 = rp[(size_t)(2 * j) * HWSZ];
            const float v1 = rp[(size_t)(2 * j + 1) * HWSZ];
            w[j] = __builtin_bit_cast(unsigned int, half2v{(_Float16)v0, (_Float16)v1});
        }
        unsigned int* dst = &rfs[rr][DMAX + x][0];
        *(uint4*)(dst + 0) = make_uint4(w[0], w[1], w[2], w[3]);
        *(uint4*)(dst + 4) = make_uint4(w[4], w[5], w[6], w[7]);
        *(uint2*)(dst + 8) = make_uint2(w[8], w[9]);
    }

    // lf for this thread's (row, 2i / 2i+1): float2 loads (fully coalesced)
    half2v L0[10], L1[10];
    {
        const float* lp = lf + gbase + (size_t)(y0 + r) * WW + 2 * i;
#pragma unroll
        for (int j = 0; j < 10; ++j) {
            const float2 c0 = *(const float2*)(lp + (size_t)(2 * j) * HWSZ);
            const float2 c1 = *(const float2*)(lp + (size_t)(2 * j + 1) * HWSZ);
            L0[j] = half2v{(_Float16)c0.x, (_Float16)c1.x};   // x = 2i,   ch 2j,2j+1
            L1[j] = half2v{(_Float16)c0.y, (_Float16)c1.y};   // x = 2i+1, ch 2j,2j+1
        }
    }
    __syncthreads();

    const float scale = 0.22360679774997896f;   // 1/sqrt(20)
    float* op = out + (size_t)bg * DMAX * HWSZ + (size_t)(y0 + r) * WW + 2 * i;
    const unsigned int (*buf)[SPAD] = rfs[r];

#pragma unroll 4
    for (int d = 0; d < DMAX; ++d) {
        const unsigned int* pA = &buf[2 * i + DMAX - d][0];   // slot for x=2i
        const uint4 a0 = *(const uint4*)(pA + 0);
        const uint4 a1 = *(const uint4*)(pA + 4);
        const uint2 a2 = *(const uint2*)(pA + 8);
        const uint4 b0 = *(const uint4*)(pA + SPAD + 0);      // slot for x=2i+1
        const uint4 b1 = *(const uint4*)(pA + SPAD + 4);
        const uint2 b2 = *(const uint2*)(pA + SPAD + 8);

        float sa = 0.f, sb = 0.f, ta = 0.f, tb = 0.f;
        sa = __builtin_amdgcn_fdot2(L0[0], BC(a0.x), sa, false);
        sb = __builtin_amdgcn_fdot2(L0[1], BC(a0.y), sb, false);
        sa = __builtin_amdgcn_fdot2(L0[2], BC(a0.z), sa, false);
        sb = __builtin_amdgcn_fdot2(L0[3], BC(a0.w), sb, false);
        sa = __builtin_amdgcn_fdot2(L0[4], BC(a1.x), sa, false);
        sb = __builtin_amdgcn_fdot2(L0[5], BC(a1.y), sb, false);
        sa = __builtin_amdgcn_fdot2(L0[6], BC(a1.z), sa, false);
        sb = __builtin_amdgcn_fdot2(L0[7], BC(a1.w), sb, false);
        sa = __builtin_amdgcn_fdot2(L0[8], BC(a2.x), sa, false);
        sb = __builtin_amdgcn_fdot2(L0[9], BC(a2.y), sb, false);
        ta = __builtin_amdgcn_fdot2(L1[0], BC(b0.x), ta, false);
        tb = __builtin_amdgcn_fdot2(L1[1], BC(b0.y), tb, false);
        ta = __builtin_amdgcn_fdot2(L1[2], BC(b0.z), ta, false);
        tb = __builtin_amdgcn_fdot2(L1[3], BC(b0.w), tb, false);
        ta = __builtin_amdgcn_fdot2(L1[4], BC(b1.x), ta, false);
        tb = __builtin_amdgcn_fdot2(L1[5], BC(b1.y), tb, false);
        ta = __builtin_amdgcn_fdot2(L1[6], BC(b1.z), ta, false);
        tb = __builtin_amdgcn_fdot2(L1[7], BC(b1.w), tb, false);
        ta = __builtin_amdgcn_fdot2(L1[8], BC(b2.x), ta, false);
        tb = __builtin_amdgcn_fdot2(L1[9], BC(b2.y), tb, false);

        *(float2*)(op + (size_t)d * HWSZ) = make_float2((sa + sb) * scale, (ta + tb) * scale);
    }
}

extern "C" void kernel_launch(void* const* d_in, const int* in_sizes, int n_in,
                              void* d_out, int out_size, void* d_ws, size_t ws_size,
                              hipStream_t stream) {
    const float* lf = (const float*)d_in[0];
    const float* rf = (const float*)d_in[1];
    float* out = (float*)d_out;

    const int grid = BSZ * NHEAD * (HH / NROW);  // 3072 blocks
    gwc_kernel<<<grid, 192, 0, stream>>>(lf, rf, out);
}

// Round 10
// 78.141 us; speedup vs baseline: 1.8988x; 1.3372x over previous
//
#include <hip/hip_runtime.h>

// Problem constants (fixed by setup_inputs)
#define BSZ   4
#define CCH   320
#define HH    96
#define WW    192
#define NHEAD 16
#define NC    20          // channels per group = 320/16
#define DMAX  64
#define HWSZ  (HH * WW)
#define NSLOT (WW + DMAX) // 256 slots (64 zero pad + 192 data)
#define SPAD  12          // uints per slot: 10 half2 + 2 pad -> 48 B, 16B-aligned
#define NROW  2           // rows per block
#define TPR   96          // threads per row; thread covers x = 2i, 2i+1

typedef _Float16 half2v __attribute__((ext_vector_type(2)));
typedef float    f32x2  __attribute__((ext_vector_type(2)));
#define BC(u) __builtin_bit_cast(half2v, u)

// R9 with ONE change: output stores are NONTEMPORAL (global_store_dwordx2 nt).
// The 302 MB output stream is write-once streaming data; letting it allocate
// in L2/L3 evicts the (L3-resident, reused-across-replays) inputs and burns
// L3 fill/evict BW. nt stores keep inputs cached (FETCH -> ~0) and stream
// writes at fill-kernel efficiency.
__global__ __launch_bounds__(192) void gwc_kernel(const float* __restrict__ lf,
                                                  const float* __restrict__ rf,
                                                  float* __restrict__ out) {
    __shared__ __align__(16) unsigned int rfs[NROW][NSLOT][SPAD];   // 24576 B

    const int tid = threadIdx.x;
    const int r   = tid / TPR;        // row within block
    const int i   = tid % TPR;        // x-pair; x = 2i, 2i+1
    int bid = blockIdx.x;
    const int yp = bid % (HH / NROW); bid /= (HH / NROW);
    const int bg = bid;               // combined (b*NHEAD + g)
    const int y0 = yp * NROW;

    // zero the left pads (slots 0..63 of both rows)
    for (int k = tid; k < NROW * DMAX * SPAD; k += 192) {
        const int rr  = k / (DMAX * SPAD);
        const int off = k % (DMAX * SPAD);
        (&rfs[rr][0][0])[off] = 0u;
    }

    const size_t gbase = (size_t)bg * NC * HWSZ;

    // stage rf: item = (row, x); 2*192 items, 20 scalar f32 -> 10 half2 -> 48 B
    for (int it = tid; it < NROW * WW; it += 192) {
        const int rr = it / WW, x = it % WW;
        const float* rp = rf + gbase + (size_t)(y0 + rr) * WW + x;
        unsigned int w[10];
#pragma unroll
        for (int j = 0; j < 10; ++j) {
            const float v0 = rp[(size_t)(2 * j) * HWSZ];
            const float v1 = rp[(size_t)(2 * j + 1) * HWSZ];
            w[j] = __builtin_bit_cast(unsigned int, half2v{(_Float16)v0, (_Float16)v1});
        }
        unsigned int* dst = &rfs[rr][DMAX + x][0];
        *(uint4*)(dst + 0) = make_uint4(w[0], w[1], w[2], w[3]);
        *(uint4*)(dst + 4) = make_uint4(w[4], w[5], w[6], w[7]);
        *(uint2*)(dst + 8) = make_uint2(w[8], w[9]);
    }

    // lf for this thread's (row, 2i / 2i+1): float2 loads (fully coalesced)
    half2v L0[10], L1[10];
    {
        const float* lp = lf + gbase + (size_t)(y0 + r) * WW + 2 * i;
#pragma unroll
        for (int j = 0; j < 10; ++j) {
            const float2 c0 = *(const float2*)(lp + (size_t)(2 * j) * HWSZ);
            const float2 c1 = *(const float2*)(lp + (size_t)(2 * j + 1) * HWSZ);
            L0[j] = half2v{(_Float16)c0.x, (_Float16)c1.x};   // x = 2i,   ch 2j,2j+1
            L1[j] = half2v{(_Float16)c0.y, (_Float16)c1.y};   // x = 2i+1, ch 2j,2j+1
        }
    }
    __syncthreads();

    const float scale = 0.22360679774997896f;   // 1/sqrt(20)
    float* op = out + (size_t)bg * DMAX * HWSZ + (size_t)(y0 + r) * WW + 2 * i;
    const unsigned int (*buf)[SPAD] = rfs[r];

#pragma unroll 4
    for (int d = 0; d < DMAX; ++d) {
        const unsigned int* pA = &buf[2 * i + DMAX - d][0];   // slot for x=2i
        const uint4 a0 = *(const uint4*)(pA + 0);
        const uint4 a1 = *(const uint4*)(pA + 4);
        const uint2 a2 = *(const uint2*)(pA + 8);
        const uint4 b0 = *(const uint4*)(pA + SPAD + 0);      // slot for x=2i+1
        const uint4 b1 = *(const uint4*)(pA + SPAD + 4);
        const uint2 b2 = *(const uint2*)(pA + SPAD + 8);

        float sa = 0.f, sb = 0.f, ta = 0.f, tb = 0.f;
        sa = __builtin_amdgcn_fdot2(L0[0], BC(a0.x), sa, false);
        sb = __builtin_amdgcn_fdot2(L0[1], BC(a0.y), sb, false);
        sa = __builtin_amdgcn_fdot2(L0[2], BC(a0.z), sa, false);
        sb = __builtin_amdgcn_fdot2(L0[3], BC(a0.w), sb, false);
        sa = __builtin_amdgcn_fdot2(L0[4], BC(a1.x), sa, false);
        sb = __builtin_amdgcn_fdot2(L0[5], BC(a1.y), sb, false);
        sa = __builtin_amdgcn_fdot2(L0[6], BC(a1.z), sa, false);
        sb = __builtin_amdgcn_fdot2(L0[7], BC(a1.w), sb, false);
        sa = __builtin_amdgcn_fdot2(L0[8], BC(a2.x), sa, false);
        sb = __builtin_amdgcn_fdot2(L0[9], BC(a2.y), sb, false);
        ta = __builtin_amdgcn_fdot2(L1[0], BC(b0.x), ta, false);
        tb = __builtin_amdgcn_fdot2(L1[1], BC(b0.y), tb, false);
        ta = __builtin_amdgcn_fdot2(L1[2], BC(b0.z), ta, false);
        tb = __builtin_amdgcn_fdot2(L1[3], BC(b0.w), tb, false);
        ta = __builtin_amdgcn_fdot2(L1[4], BC(b1.x), ta, false);
        tb = __builtin_amdgcn_fdot2(L1[5], BC(b1.y), tb, false);
        ta = __builtin_amdgcn_fdot2(L1[6], BC(b1.z), ta, false);
        tb = __builtin_amdgcn_fdot2(L1[7], BC(b1.w), tb, false);
        ta = __builtin_amdgcn_fdot2(L1[8], BC(b2.x), ta, false);
        tb = __builtin_amdgcn_fdot2(L1[9], BC(b2.y), tb, false);

        const f32x2 v = {(sa + sb) * scale, (ta + tb) * scale};
        __builtin_nontemporal_store(v, (f32x2*)(op + (size_t)d * HWSZ));
    }
}

extern "C" void kernel_launch(void* const* d_in, const int* in_sizes, int n_in,
                              void* d_out, int out_size, void* d_ws, size_t ws_size,
                              hipStream_t stream) {
    const float* lf = (const float*)d_in[0];
    const float* rf = (const float*)d_in[1];
    float* out = (float*)d_out;

    const int grid = BSZ * NHEAD * (HH / NROW);  // 3072 blocks
    gwc_kernel<<<grid, 192, 0, stream>>>(lf, rf, out);
}